// Round 1
// baseline (8348.802 us; speedup 1.0000x reference)
//
#include <hip/hip_runtime.h>
#include <math.h>

#define N_NODES 50000
#define E_ORIG  800000
#define E_TOT   850000   // + self loops

// ---------------- fp32 GEMM: C[M,N] = A[M,K] @ B[K,N], row-major ----------------
// 64x64 tile, 256 threads, 4x4 microtile. M ragged (guarded), N%64==0, K%16==0.
__global__ __launch_bounds__(256) void gemm_nn(const float* __restrict__ A,
                                               const float* __restrict__ B,
                                               float* __restrict__ C,
                                               int M, int N, int K)
{
    __shared__ float sA[64][17];   // +1 pad: breaks 4-way bank conflict on column reads
    __shared__ float sB[16][64];
    const int tx = threadIdx.x, ty = threadIdx.y;
    const int t  = ty * 16 + tx;
    const int m0 = blockIdx.y * 64;
    const int n0 = blockIdx.x * 64;
    float acc[4][4] = {};
    for (int k0 = 0; k0 < K; k0 += 16) {
#pragma unroll
        for (int r = 0; r < 4; ++r) {               // A tile 64x16
            int li = t + r * 256;
            int row = li >> 4, col = li & 15;
            int gm = m0 + row;
            sA[row][col] = (gm < M) ? A[(size_t)gm * K + k0 + col] : 0.f;
        }
#pragma unroll
        for (int r = 0; r < 4; ++r) {               // B tile 16x64
            int li = t + r * 256;
            int row = li >> 6, col = li & 63;
            sB[row][col] = B[(size_t)(k0 + row) * N + n0 + col];
        }
        __syncthreads();
#pragma unroll
        for (int kk = 0; kk < 16; ++kk) {
            float a[4], b[4];
#pragma unroll
            for (int i = 0; i < 4; ++i) a[i] = sA[ty * 4 + i][kk];
#pragma unroll
            for (int j = 0; j < 4; ++j) b[j] = sB[kk][tx * 4 + j];
#pragma unroll
            for (int i = 0; i < 4; ++i)
#pragma unroll
                for (int j = 0; j < 4; ++j)
                    acc[i][j] = fmaf(a[i], b[j], acc[i][j]);
        }
        __syncthreads();
    }
#pragma unroll
    for (int i = 0; i < 4; ++i) {
        int gm = m0 + ty * 4 + i;
        if (gm < M) {
#pragma unroll
            for (int j = 0; j < 4; ++j)
                C[(size_t)gm * N + n0 + tx * 4 + j] = acc[i][j];
        }
    }
}

// ---------------- attention logits: al_s[n,h] = sum_c h[n,h,c]*a_src[h,c] ----------------
__global__ void logits_kernel(const float* __restrict__ h,
                              const float* __restrict__ a_src,
                              const float* __restrict__ a_dst,
                              float* __restrict__ al_s, float* __restrict__ al_d,
                              int H, int C)
{
    int i = blockIdx.x * blockDim.x + threadIdx.x;
    if (i >= N_NODES * H) return;
    int n = i / H, hh = i % H;
    const float* hp = h + (size_t)n * H * C + (size_t)hh * C;
    const float* as = a_src + hh * C;
    const float* ad = a_dst + hh * C;
    float ss = 0.f, sd = 0.f;
    for (int c = 0; c < C; ++c) { float v = hp[c]; ss = fmaf(v, as[c], ss); sd = fmaf(v, ad[c], sd); }
    al_s[i] = ss; al_d[i] = sd;
}

// ---------------- softmax denominator: den[d,h] += exp(leaky_relu(al_s[s]+al_d[d])) ----------------
// (no segment-max: softmax is shift-invariant and logits are O(1) -> no overflow in fp32)
__global__ void edge_den_kernel(const int* __restrict__ ei,
                                const float* __restrict__ al_s,
                                const float* __restrict__ al_d,
                                float* __restrict__ den, int H)
{
    int e = blockIdx.x * blockDim.x + threadIdx.x;
    if (e >= E_TOT) return;
    int s, d;
    if (e < E_ORIG) { s = ei[e]; d = ei[E_ORIG + e]; } else { s = d = e - E_ORIG; }
    for (int hh = 0; hh < H; ++hh) {
        float v = al_s[s * H + hh] + al_d[d * H + hh];
        v = v > 0.f ? v : 0.2f * v;
        unsafeAtomicAdd(&den[d * H + hh], expf(v));
    }
}

// ---------------- message scatter: out[d,h,:] += alpha * h[s,h,:] ----------------
// one float4 (4 channels) per lane; HC/4 lanes per edge. alpha recomputed (cached scalar loads).
template<int HC, int C>
__global__ __launch_bounds__(256) void edge_scatter_kernel(const int* __restrict__ ei,
                                                           const float* __restrict__ h,
                                                           const float* __restrict__ al_s,
                                                           const float* __restrict__ al_d,
                                                           const float* __restrict__ den,
                                                           float* __restrict__ out)
{
    constexpr int TPE = HC / 4;        // threads per edge
    constexpr int EPB = 256 / TPE;     // edges per block
    constexpr int H   = HC / C;
    int t = threadIdx.x;
    int e = blockIdx.x * EPB + t / TPE;
    if (e >= E_TOT) return;
    int lane = t % TPE;
    int s, d;
    if (e < E_ORIG) { s = ei[e]; d = ei[E_ORIG + e]; } else { s = d = e - E_ORIG; }
    int c0 = lane * 4;
    int head = c0 / C;
    float v = al_s[s * H + head] + al_d[d * H + head];
    v = v > 0.f ? v : 0.2f * v;
    float alpha = expf(v) / den[d * H + head];
    float4 hv = *reinterpret_cast<const float4*>(h + (size_t)s * HC + c0);
    float* op = out + (size_t)d * HC + c0;
    unsafeAtomicAdd(op + 0, hv.x * alpha);
    unsafeAtomicAdd(op + 1, hv.y * alpha);
    unsafeAtomicAdd(op + 2, hv.z * alpha);
    unsafeAtomicAdd(op + 3, hv.w * alpha);
}

// ---------------- epilogues ----------------
__global__ void bias_bn_elu_kernel(float* __restrict__ io, const float* __restrict__ bias,
                                   const float* __restrict__ gamma, const float* __restrict__ beta,
                                   const float* __restrict__ mean, const float* __restrict__ var,
                                   int F)
{
    int i = blockIdx.x * blockDim.x + threadIdx.x;
    if (i >= N_NODES * F) return;
    int c = i % F;
    float v = io[i] + bias[c];
    v = (v - mean[c]) * rsqrtf(var[c] + 1e-5f) * gamma[c] + beta[c];
    io[i] = v > 0.f ? v : expm1f(v);   // ELU(alpha=1)
}

__global__ void bias_add_kernel(float* __restrict__ io, const float* __restrict__ bias, int F)
{
    int i = blockIdx.x * blockDim.x + threadIdx.x;
    if (i >= N_NODES * F) return;
    io[i] += bias[i % F];
}

extern "C" void kernel_launch(void* const* d_in, const int* in_sizes, int n_in,
                              void* d_out, int out_size, void* d_ws, size_t ws_size,
                              hipStream_t stream)
{
    const float* x   = (const float*)d_in[0];
    const int*   ei  = (const int*)d_in[1];
    const float* W1  = (const float*)d_in[2];
    const float* as1 = (const float*)d_in[3];
    const float* ad1 = (const float*)d_in[4];
    const float* b1  = (const float*)d_in[5];
    const float* g1  = (const float*)d_in[6];
    const float* be1 = (const float*)d_in[7];
    const float* mn1 = (const float*)d_in[8];
    const float* vr1 = (const float*)d_in[9];
    const float* W2  = (const float*)d_in[10];
    const float* as2 = (const float*)d_in[11];
    const float* ad2 = (const float*)d_in[12];
    const float* b2  = (const float*)d_in[13];
    const float* g2  = (const float*)d_in[14];
    const float* be2 = (const float*)d_in[15];
    const float* mn2 = (const float*)d_in[16];
    const float* vr2 = (const float*)d_in[17];
    const float* W3  = (const float*)d_in[18];
    const float* as3 = (const float*)d_in[19];
    const float* ad3 = (const float*)d_in[20];
    const float* b3  = (const float*)d_in[21];

    char* p = (char*)d_ws;
    float* hbuf = (float*)p; p += (size_t)N_NODES * 256 * 4;   // 51.2 MB: h = in @ W
    float* obuf = (float*)p; p += (size_t)N_NODES * 256 * 4;   // 51.2 MB: aggregated layer output
    float* als  = (float*)p; p += (size_t)N_NODES * 8 * 4;
    float* ald  = (float*)p; p += (size_t)N_NODES * 8 * 4;
    float* den  = (float*)p; p += (size_t)N_NODES * 8 * 4;

    float* out = (float*)d_out;
    dim3 bl16(16, 16);

    // ----- layer 1: GAT(128 -> 8x32) + BN + ELU -----
    {
        dim3 gr(256 / 64, (N_NODES + 63) / 64);
        gemm_nn<<<gr, bl16, 0, stream>>>(x, W1, hbuf, N_NODES, 256, 128);
        int nh = N_NODES * 8;
        logits_kernel<<<(nh + 255) / 256, 256, 0, stream>>>(hbuf, as1, ad1, als, ald, 8, 32);
        hipMemsetAsync(den, 0, (size_t)nh * 4, stream);
        hipMemsetAsync(obuf, 0, (size_t)N_NODES * 256 * 4, stream);
        edge_den_kernel<<<(E_TOT + 255) / 256, 256, 0, stream>>>(ei, als, ald, den, 8);
        edge_scatter_kernel<256, 32><<<E_TOT / 4, 256, 0, stream>>>(ei, hbuf, als, ald, den, obuf);
        bias_bn_elu_kernel<<<(N_NODES * 256 + 255) / 256, 256, 0, stream>>>(obuf, b1, g1, be1, mn1, vr1, 256);
    }
    // ----- layer 2: GAT(256 -> 8x32) + BN + ELU -----
    {
        dim3 gr(256 / 64, (N_NODES + 63) / 64);
        gemm_nn<<<gr, bl16, 0, stream>>>(obuf, W2, hbuf, N_NODES, 256, 256);
        int nh = N_NODES * 8;
        logits_kernel<<<(nh + 255) / 256, 256, 0, stream>>>(hbuf, as2, ad2, als, ald, 8, 32);
        hipMemsetAsync(den, 0, (size_t)nh * 4, stream);
        hipMemsetAsync(obuf, 0, (size_t)N_NODES * 256 * 4, stream);  // gemm already consumed obuf
        edge_den_kernel<<<(E_TOT + 255) / 256, 256, 0, stream>>>(ei, als, ald, den, 8);
        edge_scatter_kernel<256, 32><<<E_TOT / 4, 256, 0, stream>>>(ei, hbuf, als, ald, den, obuf);
        bias_bn_elu_kernel<<<(N_NODES * 256 + 255) / 256, 256, 0, stream>>>(obuf, b2, g2, be2, mn2, vr2, 256);
    }
    // ----- layer 3: GAT(256 -> 1x128), heads=1 so mean == identity -----
    {
        dim3 gr(128 / 64, (N_NODES + 63) / 64);
        gemm_nn<<<gr, bl16, 0, stream>>>(obuf, W3, hbuf, N_NODES, 128, 256);
        logits_kernel<<<(N_NODES + 255) / 256, 256, 0, stream>>>(hbuf, as3, ad3, als, ald, 1, 128);
        hipMemsetAsync(den, 0, (size_t)N_NODES * 4, stream);
        hipMemsetAsync(out, 0, (size_t)N_NODES * 128 * 4, stream);
        edge_den_kernel<<<(E_TOT + 255) / 256, 256, 0, stream>>>(ei, als, ald, den, 1);
        edge_scatter_kernel<128, 128><<<E_TOT / 8, 256, 0, stream>>>(ei, hbuf, als, ald, den, out);
        bias_add_kernel<<<(N_NODES * 128 + 255) / 256, 256, 0, stream>>>(out, b3, 128);
    }
}

// Round 2
// 1230.417 us; speedup vs baseline: 6.7853x; 6.7853x over previous
//
#include <hip/hip_runtime.h>
#include <math.h>

#define N_NODES 50000
#define E_ORIG  800000
#define E_TOT   850000   // + self loops

// ---------------- fp32 GEMM: C[M,N] = A[M,K] @ B[K,N], row-major ----------------
__global__ __launch_bounds__(256) void gemm_nn(const float* __restrict__ A,
                                               const float* __restrict__ B,
                                               float* __restrict__ C,
                                               int M, int N, int K)
{
    __shared__ float sA[64][17];
    __shared__ float sB[16][64];
    const int tx = threadIdx.x, ty = threadIdx.y;
    const int t  = ty * 16 + tx;
    const int m0 = blockIdx.y * 64;
    const int n0 = blockIdx.x * 64;
    float acc[4][4] = {};
    for (int k0 = 0; k0 < K; k0 += 16) {
#pragma unroll
        for (int r = 0; r < 4; ++r) {
            int li = t + r * 256;
            int row = li >> 4, col = li & 15;
            int gm = m0 + row;
            sA[row][col] = (gm < M) ? A[(size_t)gm * K + k0 + col] : 0.f;
        }
#pragma unroll
        for (int r = 0; r < 4; ++r) {
            int li = t + r * 256;
            int row = li >> 6, col = li & 63;
            sB[row][col] = B[(size_t)(k0 + row) * N + n0 + col];
        }
        __syncthreads();
#pragma unroll
        for (int kk = 0; kk < 16; ++kk) {
            float a[4], b[4];
#pragma unroll
            for (int i = 0; i < 4; ++i) a[i] = sA[ty * 4 + i][kk];
#pragma unroll
            for (int j = 0; j < 4; ++j) b[j] = sB[kk][tx * 4 + j];
#pragma unroll
            for (int i = 0; i < 4; ++i)
#pragma unroll
                for (int j = 0; j < 4; ++j)
                    acc[i][j] = fmaf(a[i], b[j], acc[i][j]);
        }
        __syncthreads();
    }
#pragma unroll
    for (int i = 0; i < 4; ++i) {
        int gm = m0 + ty * 4 + i;
        if (gm < M) {
#pragma unroll
            for (int j = 0; j < 4; ++j)
                C[(size_t)gm * N + n0 + tx * 4 + j] = acc[i][j];
        }
    }
}

// ---------------- attention logits ----------------
__global__ void logits_kernel(const float* __restrict__ h,
                              const float* __restrict__ a_src,
                              const float* __restrict__ a_dst,
                              float* __restrict__ al_s, float* __restrict__ al_d,
                              int H, int C)
{
    int i = blockIdx.x * blockDim.x + threadIdx.x;
    if (i >= N_NODES * H) return;
    int n = i / H, hh = i % H;
    const float* hp = h + (size_t)n * H * C + (size_t)hh * C;
    const float* as = a_src + hh * C;
    const float* ad = a_dst + hh * C;
    float ss = 0.f, sd = 0.f;
    for (int c = 0; c < C; ++c) { float v = hp[c]; ss = fmaf(v, as[c], ss); sd = fmaf(v, ad[c], sd); }
    al_s[i] = ss; al_d[i] = sd;
}

// ---------------- CSR build: degree histogram, scan, fill ----------------
__global__ void deg_kernel(const int* __restrict__ ei, int* __restrict__ deg)
{
    int e = blockIdx.x * blockDim.x + threadIdx.x;
    if (e >= E_TOT) return;
    int d = (e < E_ORIG) ? ei[E_ORIG + e] : e - E_ORIG;
    atomicAdd(&deg[d], 1);
}

#define SCAN_T 1024
__global__ __launch_bounds__(SCAN_T) void scan_kernel(const int* __restrict__ deg,
                                                      int* __restrict__ row_ptr,
                                                      int* __restrict__ cursor)
{
    __shared__ int sums[SCAN_T];
    int t = threadIdx.x;
    const int chunk = (N_NODES + SCAN_T - 1) / SCAN_T;   // 49
    int beg = t * chunk;
    int end = beg + chunk; if (end > N_NODES) end = N_NODES;
    int s = 0;
    for (int i = beg; i < end; ++i) s += deg[i];
    sums[t] = s;
    __syncthreads();
    for (int off = 1; off < SCAN_T; off <<= 1) {
        int v = (t >= off) ? sums[t - off] : 0;
        __syncthreads();
        sums[t] += v;
        __syncthreads();
    }
    int run = (t > 0) ? sums[t - 1] : 0;   // exclusive prefix of this chunk
    for (int i = beg; i < end; ++i) {
        row_ptr[i] = run; cursor[i] = run;
        run += deg[i];
    }
    if (t == SCAN_T - 1) row_ptr[N_NODES] = run;
}

__global__ void fill_kernel(const int* __restrict__ ei, int* __restrict__ cursor,
                            int* __restrict__ col)
{
    int e = blockIdx.x * blockDim.x + threadIdx.x;
    if (e >= E_TOT) return;
    int s, d;
    if (e < E_ORIG) { s = ei[e]; d = ei[E_ORIG + e]; } else { s = d = e - E_ORIG; }
    int pos = atomicAdd(&cursor[d], 1);
    col[pos] = s;
}

// ---------------- fused gather + softmax + epilogue ----------------
// one dst node per HC threads; thread = channel. den accumulated redundantly per thread.
template<int HC, int C, int H, bool BN>
__global__ __launch_bounds__(256) void gat_gather(const int* __restrict__ row_ptr,
                                                  const int* __restrict__ col,
                                                  const float* __restrict__ h,
                                                  const float* __restrict__ al_s,
                                                  const float* __restrict__ al_d,
                                                  const float* __restrict__ bias,
                                                  const float* __restrict__ gamma,
                                                  const float* __restrict__ beta,
                                                  const float* __restrict__ mean,
                                                  const float* __restrict__ var,
                                                  float* __restrict__ out)
{
    constexpr int NPB = 256 / HC;
    int n = blockIdx.x * NPB + threadIdx.x / HC;
    if (n >= N_NODES) return;
    int c = threadIdx.x % HC;
    int head = c / C;
    float aldn = al_d[n * H + head];
    int beg = row_ptr[n], end = row_ptr[n + 1];
    float acc = 0.f, den = 0.f;
    int s_next = (beg < end) ? col[beg] : 0;
    for (int e = beg; e < end; ++e) {
        int s = s_next;
        if (e + 1 < end) s_next = col[e + 1];
        float v = al_s[s * H + head] + aldn;
        v = v > 0.f ? v : 0.2f * v;
        float w = expf(v);
        den += w;
        acc = fmaf(w, h[(size_t)s * HC + c], acc);
    }
    float r = acc / den + bias[c];
    if (BN) {
        r = (r - mean[c]) * rsqrtf(var[c] + 1e-5f) * gamma[c] + beta[c];
        r = r > 0.f ? r : expm1f(r);   // ELU
    }
    out[(size_t)n * HC + c] = r;
}

extern "C" void kernel_launch(void* const* d_in, const int* in_sizes, int n_in,
                              void* d_out, int out_size, void* d_ws, size_t ws_size,
                              hipStream_t stream)
{
    const float* x   = (const float*)d_in[0];
    const int*   ei  = (const int*)d_in[1];
    const float* W1  = (const float*)d_in[2];
    const float* as1 = (const float*)d_in[3];
    const float* ad1 = (const float*)d_in[4];
    const float* b1  = (const float*)d_in[5];
    const float* g1  = (const float*)d_in[6];
    const float* be1 = (const float*)d_in[7];
    const float* mn1 = (const float*)d_in[8];
    const float* vr1 = (const float*)d_in[9];
    const float* W2  = (const float*)d_in[10];
    const float* as2 = (const float*)d_in[11];
    const float* ad2 = (const float*)d_in[12];
    const float* b2  = (const float*)d_in[13];
    const float* g2  = (const float*)d_in[14];
    const float* be2 = (const float*)d_in[15];
    const float* mn2 = (const float*)d_in[16];
    const float* vr2 = (const float*)d_in[17];
    const float* W3  = (const float*)d_in[18];
    const float* as3 = (const float*)d_in[19];
    const float* ad3 = (const float*)d_in[20];
    const float* b3  = (const float*)d_in[21];

    char* p = (char*)d_ws;
    float* hbuf    = (float*)p; p += (size_t)N_NODES * 256 * 4;   // 51.2 MB
    float* obuf    = (float*)p; p += (size_t)N_NODES * 256 * 4;   // 51.2 MB
    float* als     = (float*)p; p += (size_t)N_NODES * 8 * 4;
    float* ald     = (float*)p; p += (size_t)N_NODES * 8 * 4;
    int*   row_ptr = (int*)p;   p += (size_t)(N_NODES + 1) * 4;
    int*   col     = (int*)p;   p += (size_t)E_TOT * 4;
    // deg/cursor alias hbuf: dead before gemm1 writes hbuf (stream-ordered)
    int*   deg     = (int*)hbuf;
    int*   cursor  = deg + N_NODES;

    float* out = (float*)d_out;
    dim3 bl16(16, 16);

    // ----- CSR build (once; shared by all 3 layers) -----
    hipMemsetAsync(deg, 0, (size_t)N_NODES * 4, stream);
    deg_kernel<<<(E_TOT + 255) / 256, 256, 0, stream>>>(ei, deg);
    scan_kernel<<<1, SCAN_T, 0, stream>>>(deg, row_ptr, cursor);
    fill_kernel<<<(E_TOT + 255) / 256, 256, 0, stream>>>(ei, cursor, col);

    // ----- layer 1: GAT(128 -> 8x32) + BN + ELU -----
    {
        dim3 gr(256 / 64, (N_NODES + 63) / 64);
        gemm_nn<<<gr, bl16, 0, stream>>>(x, W1, hbuf, N_NODES, 256, 128);
        int nh = N_NODES * 8;
        logits_kernel<<<(nh + 255) / 256, 256, 0, stream>>>(hbuf, as1, ad1, als, ald, 8, 32);
        gat_gather<256, 32, 8, true><<<N_NODES, 256, 0, stream>>>(
            row_ptr, col, hbuf, als, ald, b1, g1, be1, mn1, vr1, obuf);
    }
    // ----- layer 2: GAT(256 -> 8x32) + BN + ELU -----
    {
        dim3 gr(256 / 64, (N_NODES + 63) / 64);
        gemm_nn<<<gr, bl16, 0, stream>>>(obuf, W2, hbuf, N_NODES, 256, 256);
        int nh = N_NODES * 8;
        logits_kernel<<<(nh + 255) / 256, 256, 0, stream>>>(hbuf, as2, ad2, als, ald, 8, 32);
        gat_gather<256, 32, 8, true><<<N_NODES, 256, 0, stream>>>(
            row_ptr, col, hbuf, als, ald, b2, g2, be2, mn2, vr2, obuf);
    }
    // ----- layer 3: GAT(256 -> 1x128), heads=1 (mean == identity) -----
    {
        dim3 gr(128 / 64, (N_NODES + 63) / 64);
        gemm_nn<<<gr, bl16, 0, stream>>>(obuf, W3, hbuf, N_NODES, 128, 256);
        logits_kernel<<<(N_NODES + 255) / 256, 256, 0, stream>>>(hbuf, as3, ad3, als, ald, 1, 128);
        gat_gather<128, 128, 1, false><<<(N_NODES + 1) / 2, 256, 0, stream>>>(
            row_ptr, col, hbuf, als, ald, b3, nullptr, nullptr, nullptr, nullptr, out);
    }
}

// Round 3
// 931.378 us; speedup vs baseline: 8.9639x; 1.3211x over previous
//
#include <hip/hip_runtime.h>
#include <math.h>

#define N_NODES 50000
#define E_ORIG  800000
#define E_TOT   850000   // + self loops

typedef __attribute__((ext_vector_type(8))) short short8;   // 8 bf16 (4 VGPRs)
typedef __attribute__((ext_vector_type(4))) float f32x4;    // MFMA acc

__device__ __forceinline__ short f2bf(float f) {            // fp32 -> bf16 RNE
    unsigned u = __builtin_bit_cast(unsigned, f);
    u += 0x7FFFu + ((u >> 16) & 1u);
    return (short)(u >> 16);
}

// ---------------- bf16 MFMA GEMM: C[M,N] = A[M,K] @ W[K,N] ----------------
// A fp32 (cast to bf16 during LDS staging), Wt = W^T bf16 [N][K].
// 128x128 tile, BK=32, 256 threads = 4 waves, each wave a 64x64 quadrant (4x4 MFMA tiles).
__global__ __launch_bounds__(256) void gemm_bf16(const float* __restrict__ A,
                                                 const short* __restrict__ Wt,
                                                 float* __restrict__ C,
                                                 int M, int N, int K)
{
    __shared__ short sA[128][40];   // m-major, k inner; +8 pad: 16B-aligned rows, conflict-free frag reads
    __shared__ short sB[128][40];   // n-major, k inner
    const int t    = threadIdx.x;
    const int wave = t >> 6, lane = t & 63;
    const int quad = lane >> 4, mrow = lane & 15;
    const int m0 = blockIdx.y * 128, n0 = blockIdx.x * 128;
    const int wm = (wave & 1) * 64, wn = (wave >> 1) * 64;

    f32x4 acc[4][4] = {};

    const int ra = t >> 3, kqa = (t & 7) << 2;   // A staging: 4 rows x float4
    const int nb = t >> 1, khb = (t & 1) << 4;   // B staging: 16 shorts

    for (int k0 = 0; k0 < K; k0 += 32) {
        // stage A (fp32 -> bf16)
#pragma unroll
        for (int rr = 0; rr < 4; ++rr) {
            int row = ra + rr * 32;
            int gm = m0 + row;
            float4 v = make_float4(0.f, 0.f, 0.f, 0.f);
            if (gm < M) v = *(const float4*)(A + (size_t)gm * K + k0 + kqa);
            sA[row][kqa + 0] = f2bf(v.x);
            sA[row][kqa + 1] = f2bf(v.y);
            sA[row][kqa + 2] = f2bf(v.z);
            sA[row][kqa + 3] = f2bf(v.w);
        }
        // stage B (already bf16)
        {
            const int4* src = (const int4*)(Wt + (size_t)(n0 + nb) * K + k0 + khb);
            int4 b0 = src[0], b1 = src[1];
            *(int4*)&sB[nb][khb]     = b0;
            *(int4*)&sB[nb][khb + 8] = b1;
        }
        __syncthreads();
        short8 af[4], bfr[4];
#pragma unroll
        for (int mi = 0; mi < 4; ++mi)
            af[mi] = *(const short8*)&sA[wm + mi * 16 + mrow][quad * 8];
#pragma unroll
        for (int ni = 0; ni < 4; ++ni)
            bfr[ni] = *(const short8*)&sB[wn + ni * 16 + mrow][quad * 8];
#pragma unroll
        for (int mi = 0; mi < 4; ++mi)
#pragma unroll
            for (int ni = 0; ni < 4; ++ni)
                acc[mi][ni] = __builtin_amdgcn_mfma_f32_16x16x32_bf16(af[mi], bfr[ni], acc[mi][ni], 0, 0, 0);
        __syncthreads();
    }
    // epilogue: C/D layout col=lane&15, row=quad*4+reg
#pragma unroll
    for (int mi = 0; mi < 4; ++mi) {
#pragma unroll
        for (int ni = 0; ni < 4; ++ni) {
            int gn = n0 + wn + ni * 16 + mrow;
            int gmb = m0 + wm + mi * 16 + quad * 4;
#pragma unroll
            for (int r = 0; r < 4; ++r) {
                int gm = gmb + r;
                if (gm < M) C[(size_t)gm * N + gn] = acc[mi][ni][r];
            }
        }
    }
}

// ---------------- W^T cast: Wt[n][k] = bf16(W[k][n]) ----------------
__global__ void wtcast_kernel(const float* __restrict__ W, short* __restrict__ Wt, int K, int N)
{
    int i = blockIdx.x * blockDim.x + threadIdx.x;
    if (i >= K * N) return;
    int n = i / K, k = i % K;
    Wt[i] = f2bf(W[(size_t)k * N + n]);
}

// ---------------- attention logits ----------------
__global__ void logits_kernel(const float* __restrict__ h,
                              const float* __restrict__ a_src,
                              const float* __restrict__ a_dst,
                              float* __restrict__ al_s, float* __restrict__ al_d,
                              int H, int C)
{
    int i = blockIdx.x * blockDim.x + threadIdx.x;
    if (i >= N_NODES * H) return;
    int n = i / H, hh = i % H;
    const float* hp = h + (size_t)n * H * C + (size_t)hh * C;
    const float* as = a_src + hh * C;
    const float* ad = a_dst + hh * C;
    float ss = 0.f, sd = 0.f;
    for (int c = 0; c < C; ++c) { float v = hp[c]; ss = fmaf(v, as[c], ss); sd = fmaf(v, ad[c], sd); }
    al_s[i] = ss; al_d[i] = sd;
}

// ---------------- CSR build ----------------
__global__ void deg_kernel(const int* __restrict__ ei, int* __restrict__ deg)
{
    int e = blockIdx.x * blockDim.x + threadIdx.x;
    if (e >= E_TOT) return;
    int d = (e < E_ORIG) ? ei[E_ORIG + e] : e - E_ORIG;
    atomicAdd(&deg[d], 1);
}

#define SCAN_T 1024
__global__ __launch_bounds__(SCAN_T) void scan_kernel(const int* __restrict__ deg,
                                                      int* __restrict__ row_ptr,
                                                      int* __restrict__ cursor)
{
    __shared__ int sums[SCAN_T];
    int t = threadIdx.x;
    const int chunk = (N_NODES + SCAN_T - 1) / SCAN_T;
    int beg = t * chunk;
    int end = beg + chunk; if (end > N_NODES) end = N_NODES;
    int s = 0;
    for (int i = beg; i < end; ++i) s += deg[i];
    sums[t] = s;
    __syncthreads();
    for (int off = 1; off < SCAN_T; off <<= 1) {
        int v = (t >= off) ? sums[t - off] : 0;
        __syncthreads();
        sums[t] += v;
        __syncthreads();
    }
    int run = (t > 0) ? sums[t - 1] : 0;
    for (int i = beg; i < end; ++i) {
        row_ptr[i] = run; cursor[i] = run;
        run += deg[i];
    }
    if (t == SCAN_T - 1) row_ptr[N_NODES] = run;
}

__global__ void fill_kernel(const int* __restrict__ ei, int* __restrict__ cursor,
                            int* __restrict__ col)
{
    int e = blockIdx.x * blockDim.x + threadIdx.x;
    if (e >= E_TOT) return;
    int s, d;
    if (e < E_ORIG) { s = ei[e]; d = ei[E_ORIG + e]; } else { s = d = e - E_ORIG; }
    int pos = atomicAdd(&cursor[d], 1);
    col[pos] = s;
}

// ---------------- normalized attention weights per CSR edge ----------------
// thread = (node, head). Two passes over the segment: w + den, then divide.
template<int H>
__global__ void alpha_kernel(const int* __restrict__ row_ptr, const int* __restrict__ col,
                             const float* __restrict__ al_s, const float* __restrict__ al_d,
                             float* __restrict__ alpha)
{
    int i = blockIdx.x * blockDim.x + threadIdx.x;
    if (i >= N_NODES * H) return;
    int n = i / H, hh = i % H;
    float aldn = al_d[i];
    int beg = row_ptr[n], end = row_ptr[n + 1];
    float den = 0.f;
    for (int e = beg; e < end; ++e) {
        float v = al_s[col[e] * H + hh] + aldn;
        v = v > 0.f ? v : 0.2f * v;
        float w = expf(v);
        alpha[(size_t)e * H + hh] = w;
        den += w;
    }
    float inv = 1.f / den;
    for (int e = beg; e < end; ++e)
        alpha[(size_t)e * H + hh] *= inv;
}

// ---------------- gather: out[n,c] = sum_e alpha[e,head] * h[col[e],c] (+ epilogue) ----------------
// HC/4 threads per node, float4 per thread. For HC=256 one wave == one node (col/alpha wave-uniform).
template<int HC, int C, int H, bool BN>
__global__ __launch_bounds__(256) void gat_gather4(const int* __restrict__ row_ptr,
                                                   const int* __restrict__ col,
                                                   const float* __restrict__ h,
                                                   const float* __restrict__ alpha,
                                                   const float* __restrict__ bias,
                                                   const float* __restrict__ gamma,
                                                   const float* __restrict__ beta,
                                                   const float* __restrict__ mean,
                                                   const float* __restrict__ var,
                                                   float* __restrict__ out)
{
    constexpr int TPN = HC / 4;
    constexpr int NPB = 256 / TPN;
    int n = blockIdx.x * NPB + threadIdx.x / TPN;
    if (n >= N_NODES) return;
    int lane = threadIdx.x % TPN;
    int c0 = lane * 4;
    int head = c0 / C;
    int beg = row_ptr[n], end = row_ptr[n + 1];
    f32x4 acc = {};
    int s_next = 0; float a_next = 0.f;
    if (beg < end) { s_next = col[beg]; a_next = alpha[(size_t)beg * H + head]; }
    for (int e = beg; e < end; ++e) {
        int s = s_next; float a = a_next;
        if (e + 1 < end) { s_next = col[e + 1]; a_next = alpha[(size_t)(e + 1) * H + head]; }
        float4 hv = *(const float4*)(h + (size_t)s * HC + c0);
        acc.x = fmaf(a, hv.x, acc.x);
        acc.y = fmaf(a, hv.y, acc.y);
        acc.z = fmaf(a, hv.z, acc.z);
        acc.w = fmaf(a, hv.w, acc.w);
    }
#pragma unroll
    for (int j = 0; j < 4; ++j) {
        int c = c0 + j;
        float r = acc[j] + bias[c];
        if (BN) {
            r = (r - mean[c]) * rsqrtf(var[c] + 1e-5f) * gamma[c] + beta[c];
            r = r > 0.f ? r : expm1f(r);   // ELU
        }
        out[(size_t)n * HC + c] = r;
    }
}

extern "C" void kernel_launch(void* const* d_in, const int* in_sizes, int n_in,
                              void* d_out, int out_size, void* d_ws, size_t ws_size,
                              hipStream_t stream)
{
    const float* x   = (const float*)d_in[0];
    const int*   ei  = (const int*)d_in[1];
    const float* W1  = (const float*)d_in[2];
    const float* as1 = (const float*)d_in[3];
    const float* ad1 = (const float*)d_in[4];
    const float* b1  = (const float*)d_in[5];
    const float* g1  = (const float*)d_in[6];
    const float* be1 = (const float*)d_in[7];
    const float* mn1 = (const float*)d_in[8];
    const float* vr1 = (const float*)d_in[9];
    const float* W2  = (const float*)d_in[10];
    const float* as2 = (const float*)d_in[11];
    const float* ad2 = (const float*)d_in[12];
    const float* b2  = (const float*)d_in[13];
    const float* g2  = (const float*)d_in[14];
    const float* be2 = (const float*)d_in[15];
    const float* mn2 = (const float*)d_in[16];
    const float* vr2 = (const float*)d_in[17];
    const float* W3  = (const float*)d_in[18];
    const float* as3 = (const float*)d_in[19];
    const float* ad3 = (const float*)d_in[20];
    const float* b3  = (const float*)d_in[21];

    char* p = (char*)d_ws;
    float* hbuf    = (float*)p; p += (size_t)N_NODES * 256 * 4;     // 51.2 MB
    float* obuf    = (float*)p; p += (size_t)N_NODES * 256 * 4;     // 51.2 MB
    float* wbuf    = (float*)p; p += (size_t)E_TOT * 8 * 4;         // 27.2 MB (alpha)
    short* wtbuf   = (short*)p; p += (size_t)256 * 256 * 2;         // 128 KB (W^T bf16)
    float* als     = (float*)p; p += (size_t)N_NODES * 8 * 4;
    float* ald     = (float*)p; p += (size_t)N_NODES * 8 * 4;
    int*   row_ptr = (int*)p;   p += (size_t)(N_NODES + 1) * 4;
    int*   col     = (int*)p;   p += (size_t)E_TOT * 4;
    // deg/cursor alias wbuf (dead before alpha is first written)
    int*   deg     = (int*)wbuf;
    int*   cursor  = deg + N_NODES;

    float* out = (float*)d_out;

    // ----- CSR build (shared by all 3 layers) -----
    hipMemsetAsync(deg, 0, (size_t)N_NODES * 4, stream);
    deg_kernel<<<(E_TOT + 255) / 256, 256, 0, stream>>>(ei, deg);
    scan_kernel<<<1, SCAN_T, 0, stream>>>(deg, row_ptr, cursor);
    fill_kernel<<<(E_TOT + 255) / 256, 256, 0, stream>>>(ei, cursor, col);

    const int nh8 = N_NODES * 8;

    // ----- layer 1: GAT(128 -> 8x32) + BN + ELU -----
    wtcast_kernel<<<(128 * 256 + 255) / 256, 256, 0, stream>>>(W1, wtbuf, 128, 256);
    gemm_bf16<<<dim3(2, (N_NODES + 127) / 128), 256, 0, stream>>>(x, wtbuf, hbuf, N_NODES, 256, 128);
    logits_kernel<<<(nh8 + 255) / 256, 256, 0, stream>>>(hbuf, as1, ad1, als, ald, 8, 32);
    alpha_kernel<8><<<(nh8 + 255) / 256, 256, 0, stream>>>(row_ptr, col, als, ald, wbuf);
    gat_gather4<256, 32, 8, true><<<(N_NODES + 3) / 4, 256, 0, stream>>>(
        row_ptr, col, hbuf, wbuf, b1, g1, be1, mn1, vr1, obuf);

    // ----- layer 2: GAT(256 -> 8x32) + BN + ELU -----
    wtcast_kernel<<<(256 * 256 + 255) / 256, 256, 0, stream>>>(W2, wtbuf, 256, 256);
    gemm_bf16<<<dim3(2, (N_NODES + 127) / 128), 256, 0, stream>>>(obuf, wtbuf, hbuf, N_NODES, 256, 256);
    logits_kernel<<<(nh8 + 255) / 256, 256, 0, stream>>>(hbuf, as2, ad2, als, ald, 8, 32);
    alpha_kernel<8><<<(nh8 + 255) / 256, 256, 0, stream>>>(row_ptr, col, als, ald, wbuf);
    gat_gather4<256, 32, 8, true><<<(N_NODES + 3) / 4, 256, 0, stream>>>(
        row_ptr, col, hbuf, wbuf, b2, g2, be2, mn2, vr2, obuf);

    // ----- layer 3: GAT(256 -> 1x128), heads=1 (mean == identity) -----
    wtcast_kernel<<<(256 * 128 + 255) / 256, 256, 0, stream>>>(W3, wtbuf, 256, 128);
    gemm_bf16<<<dim3(1, (N_NODES + 127) / 128), 256, 0, stream>>>(obuf, wtbuf, hbuf, N_NODES, 128, 256);
    logits_kernel<<<(N_NODES + 255) / 256, 256, 0, stream>>>(hbuf, as3, ad3, als, ald, 1, 128);
    alpha_kernel<1><<<(N_NODES + 255) / 256, 256, 0, stream>>>(row_ptr, col, als, ald, wbuf);
    gat_gather4<128, 128, 1, false><<<(N_NODES + 7) / 8, 256, 0, stream>>>(
        row_ptr, col, hbuf, wbuf, b3, nullptr, nullptr, nullptr, nullptr, out);
}

// Round 4
// 680.500 us; speedup vs baseline: 12.2686x; 1.3687x over previous
//
#include <hip/hip_runtime.h>
#include <math.h>

#define N_NODES 50000
#define E_ORIG  800000
#define E_TOT   850000   // + self loops

typedef __attribute__((ext_vector_type(8))) short short8;   // 8 bf16 (4 VGPRs)
typedef __attribute__((ext_vector_type(4))) float f32x4;    // MFMA acc

__device__ __forceinline__ short f2bf(float f) {            // fp32 -> bf16 RNE
    unsigned u = __builtin_bit_cast(unsigned, f);
    u += 0x7FFFu + ((u >> 16) & 1u);
    return (short)(u >> 16);
}
__device__ __forceinline__ float bf2f(short s) {
    unsigned u = ((unsigned)(unsigned short)s) << 16;
    return __builtin_bit_cast(float, u);
}

// ---------------- bf16 MFMA GEMM: C[M,N] = A[M,K] @ W[K,N], all bf16, C out bf16 ----------------
// 128x128 tile, BK=32, 256 threads = 4 waves (64x64 quadrant each, 4x4 MFMA tiles).
__global__ __launch_bounds__(256) void gemm_bf16(const short* __restrict__ A,
                                                 const short* __restrict__ Wt,   // W^T [N][K]
                                                 short* __restrict__ C,
                                                 int M, int N, int K)
{
    __shared__ short sA[128][40];   // 80B rows (16B multiple): vector ops stay aligned
    __shared__ short sB[128][40];
    const int t    = threadIdx.x;
    const int wave = t >> 6, lane = t & 63;
    const int quad = lane >> 4, mrow = lane & 15;
    const int m0 = blockIdx.y * 128, n0 = blockIdx.x * 128;
    const int wm = (wave & 1) * 64, wn = (wave >> 1) * 64;

    f32x4 acc[4][4] = {};

    const int ra = t >> 2, ka = (t & 3) << 3;   // A: 2 passes of 64 rows, 8 shorts (16B) each
    const int nb = t >> 1, kb = (t & 1) << 4;   // B: 128 rows, 16 shorts per thread

    for (int k0 = 0; k0 < K; k0 += 32) {
#pragma unroll
        for (int rr = 0; rr < 2; ++rr) {
            int row = ra + rr * 64;
            int gm = m0 + row;
            int4 v = {0, 0, 0, 0};
            if (gm < M) v = *(const int4*)(A + (size_t)gm * K + k0 + ka);
            *(int4*)&sA[row][ka] = v;
        }
        {
            const int4* src = (const int4*)(Wt + (size_t)(n0 + nb) * K + k0 + kb);
            *(int4*)&sB[nb][kb]     = src[0];
            *(int4*)&sB[nb][kb + 8] = src[1];
        }
        __syncthreads();
        short8 af[4], bfr[4];
#pragma unroll
        for (int mi = 0; mi < 4; ++mi)
            af[mi] = *(const short8*)&sA[wm + mi * 16 + mrow][quad * 8];
#pragma unroll
        for (int ni = 0; ni < 4; ++ni)
            bfr[ni] = *(const short8*)&sB[wn + ni * 16 + mrow][quad * 8];
#pragma unroll
        for (int mi = 0; mi < 4; ++mi)
#pragma unroll
            for (int ni = 0; ni < 4; ++ni)
                acc[mi][ni] = __builtin_amdgcn_mfma_f32_16x16x32_bf16(af[mi], bfr[ni], acc[mi][ni], 0, 0, 0);
        __syncthreads();
    }
    // C/D layout: col = lane&15, row = quad*4 + reg
#pragma unroll
    for (int mi = 0; mi < 4; ++mi) {
#pragma unroll
        for (int ni = 0; ni < 4; ++ni) {
            int gn = n0 + wn + ni * 16 + mrow;
            int gmb = m0 + wm + mi * 16 + quad * 4;
#pragma unroll
            for (int r = 0; r < 4; ++r) {
                int gm = gmb + r;
                if (gm < M) C[(size_t)gm * N + gn] = f2bf(acc[mi][ni][r]);
            }
        }
    }
}

// ---------------- casts ----------------
__global__ void xcast_kernel(const float* __restrict__ x, short* __restrict__ xb, int total4)
{
    int i = blockIdx.x * blockDim.x + threadIdx.x;
    if (i >= total4) return;
    float4 v = ((const float4*)x)[i];
    short4 o; o.x = f2bf(v.x); o.y = f2bf(v.y); o.z = f2bf(v.z); o.w = f2bf(v.w);
    ((short4*)xb)[i] = o;
}

__global__ void wtcast_kernel(const float* __restrict__ W, short* __restrict__ Wt, int K, int N)
{
    int i = blockIdx.x * blockDim.x + threadIdx.x;
    if (i >= K * N) return;
    int n = i / K, k = i % K;
    Wt[i] = f2bf(W[(size_t)k * N + n]);
}

// ---------------- attention logits from bf16 h ----------------
template<int H, int C>
__global__ void logits_bf(const short* __restrict__ h,
                          const float* __restrict__ a_src,
                          const float* __restrict__ a_dst,
                          float* __restrict__ al_s, float* __restrict__ al_d)
{
    int i = blockIdx.x * blockDim.x + threadIdx.x;
    if (i >= N_NODES * H) return;
    int n = i / H, hh = i % H;
    const short* hp = h + (size_t)n * H * C + hh * C;
    const float* as = a_src + hh * C;
    const float* ad = a_dst + hh * C;
    float ss = 0.f, sd = 0.f;
#pragma unroll
    for (int c8 = 0; c8 < C; c8 += 8) {
        short8 hv = *(const short8*)(hp + c8);
#pragma unroll
        for (int j = 0; j < 8; ++j) {
            float v = bf2f(hv[j]);
            ss = fmaf(v, as[c8 + j], ss);
            sd = fmaf(v, ad[c8 + j], sd);
        }
    }
    al_s[i] = ss; al_d[i] = sd;
}

// ---------------- CSR build ----------------
__global__ void deg_kernel(const int* __restrict__ ei, int* __restrict__ deg)
{
    int e = blockIdx.x * blockDim.x + threadIdx.x;
    if (e >= E_TOT) return;
    int d = (e < E_ORIG) ? ei[E_ORIG + e] : e - E_ORIG;
    atomicAdd(&deg[d], 1);
}

#define SCAN_T 1024
__global__ __launch_bounds__(SCAN_T) void scan_kernel(const int* __restrict__ deg,
                                                      int* __restrict__ row_ptr,
                                                      int* __restrict__ cursor)
{
    __shared__ int sums[SCAN_T];
    int t = threadIdx.x;
    const int chunk = (N_NODES + SCAN_T - 1) / SCAN_T;
    int beg = t * chunk;
    int end = beg + chunk; if (end > N_NODES) end = N_NODES;
    int s = 0;
    for (int i = beg; i < end; ++i) s += deg[i];
    sums[t] = s;
    __syncthreads();
    for (int off = 1; off < SCAN_T; off <<= 1) {
        int v = (t >= off) ? sums[t - off] : 0;
        __syncthreads();
        sums[t] += v;
        __syncthreads();
    }
    int run = (t > 0) ? sums[t - 1] : 0;
    for (int i = beg; i < end; ++i) {
        row_ptr[i] = run; cursor[i] = run;
        run += deg[i];
    }
    if (t == SCAN_T - 1) row_ptr[N_NODES] = run;
}

__global__ void fill_kernel(const int* __restrict__ ei, int* __restrict__ cursor,
                            int* __restrict__ col, int* __restrict__ dstv)
{
    int e = blockIdx.x * blockDim.x + threadIdx.x;
    if (e >= E_TOT) return;
    int s, d;
    if (e < E_ORIG) { s = ei[e]; d = ei[E_ORIG + e]; } else { s = d = e - E_ORIG; }
    int pos = atomicAdd(&cursor[d], 1);
    col[pos] = s;
    dstv[pos] = d;
}

// ---------------- unnormalized edge weights: w[e,h] = exp(leaky_relu(al_s[s]+al_d[d])) ----------------
template<int H>
__global__ void edge_w_kernel(const int* __restrict__ col, const int* __restrict__ dstv,
                              const float* __restrict__ al_s, const float* __restrict__ al_d,
                              float* __restrict__ w)
{
    int e = blockIdx.x * blockDim.x + threadIdx.x;
    if (e >= E_TOT) return;
    int s = col[e], d = dstv[e];
#pragma unroll
    for (int h = 0; h < H; ++h) {
        float v = al_s[s * H + h] + al_d[d * H + h];
        v = v > 0.f ? v : 0.2f * v;
        w[(size_t)e * H + h] = expf(v);
    }
}

// ---------------- gather: out[n,c] = (sum_e w[e,head]*h[col[e],c]) / den (+ epilogue) ----------------
template<int HC, int C, int H, bool BN, bool OUTBF>
__global__ __launch_bounds__(256) void gat_gather_bf(const int* __restrict__ row_ptr,
                                                     const int* __restrict__ col,
                                                     const short* __restrict__ h,
                                                     const float* __restrict__ wv,
                                                     const float* __restrict__ bias,
                                                     const float* __restrict__ gamma,
                                                     const float* __restrict__ beta,
                                                     const float* __restrict__ mean,
                                                     const float* __restrict__ var,
                                                     void* __restrict__ outp)
{
    constexpr int TPN = HC / 4;        // threads per node (short4 each)
    constexpr int NPB = 256 / TPN;
    int n = blockIdx.x * NPB + threadIdx.x / TPN;
    if (n >= N_NODES) return;
    int lane = threadIdx.x % TPN;
    int c0 = lane * 4;
    int head = c0 / C;
    int beg = row_ptr[n], end = row_ptr[n + 1];
    float a0 = 0.f, a1 = 0.f, a2 = 0.f, a3 = 0.f, den = 0.f;
    int e = beg;
    for (; e + 1 < end; e += 2) {                 // 2x unroll: 2 h-loads in flight
        int s0 = col[e], s1 = col[e + 1];
        float w0 = wv[(size_t)e * H + head];
        float w1 = wv[(size_t)(e + 1) * H + head];
        short4 h0 = *(const short4*)(h + (size_t)s0 * HC + c0);
        short4 h1 = *(const short4*)(h + (size_t)s1 * HC + c0);
        den += w0 + w1;
        a0 = fmaf(w0, bf2f(h0.x), a0); a1 = fmaf(w0, bf2f(h0.y), a1);
        a2 = fmaf(w0, bf2f(h0.z), a2); a3 = fmaf(w0, bf2f(h0.w), a3);
        a0 = fmaf(w1, bf2f(h1.x), a0); a1 = fmaf(w1, bf2f(h1.y), a1);
        a2 = fmaf(w1, bf2f(h1.z), a2); a3 = fmaf(w1, bf2f(h1.w), a3);
    }
    if (e < end) {
        int s0 = col[e];
        float w0 = wv[(size_t)e * H + head];
        short4 h0 = *(const short4*)(h + (size_t)s0 * HC + c0);
        den += w0;
        a0 = fmaf(w0, bf2f(h0.x), a0); a1 = fmaf(w0, bf2f(h0.y), a1);
        a2 = fmaf(w0, bf2f(h0.z), a2); a3 = fmaf(w0, bf2f(h0.w), a3);
    }
    float inv = 1.f / den;
    float r[4] = { a0 * inv, a1 * inv, a2 * inv, a3 * inv };
#pragma unroll
    for (int j = 0; j < 4; ++j) {
        int c = c0 + j;
        float v = r[j] + bias[c];
        if (BN) {
            v = (v - mean[c]) * rsqrtf(var[c] + 1e-5f) * gamma[c] + beta[c];
            v = v > 0.f ? v : expm1f(v);   // ELU
        }
        r[j] = v;
    }
    if (OUTBF) {
        short4 o; o.x = f2bf(r[0]); o.y = f2bf(r[1]); o.z = f2bf(r[2]); o.w = f2bf(r[3]);
        *(short4*)((short*)outp + (size_t)n * HC + c0) = o;
    } else {
        *(float4*)((float*)outp + (size_t)n * HC + c0) = make_float4(r[0], r[1], r[2], r[3]);
    }
}

extern "C" void kernel_launch(void* const* d_in, const int* in_sizes, int n_in,
                              void* d_out, int out_size, void* d_ws, size_t ws_size,
                              hipStream_t stream)
{
    const float* x   = (const float*)d_in[0];
    const int*   ei  = (const int*)d_in[1];
    const float* W1  = (const float*)d_in[2];
    const float* as1 = (const float*)d_in[3];
    const float* ad1 = (const float*)d_in[4];
    const float* b1  = (const float*)d_in[5];
    const float* g1  = (const float*)d_in[6];
    const float* be1 = (const float*)d_in[7];
    const float* mn1 = (const float*)d_in[8];
    const float* vr1 = (const float*)d_in[9];
    const float* W2  = (const float*)d_in[10];
    const float* as2 = (const float*)d_in[11];
    const float* ad2 = (const float*)d_in[12];
    const float* b2  = (const float*)d_in[13];
    const float* g2  = (const float*)d_in[14];
    const float* be2 = (const float*)d_in[15];
    const float* mn2 = (const float*)d_in[16];
    const float* vr2 = (const float*)d_in[17];
    const float* W3  = (const float*)d_in[18];
    const float* as3 = (const float*)d_in[19];
    const float* ad3 = (const float*)d_in[20];
    const float* b3  = (const float*)d_in[21];

    char* p = (char*)d_ws;
    short* hbuf    = (short*)p; p += (size_t)N_NODES * 256 * 2;     // 25.6 MB (bf16 h)
    short* obuf    = (short*)p; p += (size_t)N_NODES * 256 * 2;     // 25.6 MB (bf16 layer out)
    short* xbf     = (short*)p; p += (size_t)N_NODES * 128 * 2;     // 12.8 MB (bf16 x)
    float* wbuf    = (float*)p; p += (size_t)E_TOT * 8 * 4;         // 27.2 MB (edge w)
    short* wtbuf   = (short*)p; p += (size_t)256 * 256 * 2;         // 128 KB (W^T bf16)
    float* als     = (float*)p; p += (size_t)N_NODES * 8 * 4;
    float* ald     = (float*)p; p += (size_t)N_NODES * 8 * 4;
    int*   row_ptr = (int*)p;   p += (size_t)(N_NODES + 1) * 4;
    int*   col     = (int*)p;   p += (size_t)E_TOT * 4;
    int*   dstv    = (int*)p;   p += (size_t)E_TOT * 4;
    // deg/cursor alias wbuf (dead before wbuf first written by edge_w)
    int*   deg     = (int*)wbuf;
    int*   cursor  = deg + N_NODES;

    float* out = (float*)d_out;

    // ----- CSR build (once) + x cast -----
    hipMemsetAsync(deg, 0, (size_t)N_NODES * 4, stream);
    deg_kernel<<<(E_TOT + 255) / 256, 256, 0, stream>>>(ei, deg);
    scan_kernel<<<1, SCAN_T, 0, stream>>>(deg, row_ptr, cursor);
    fill_kernel<<<(E_TOT + 255) / 256, 256, 0, stream>>>(ei, cursor, col, dstv);
    xcast_kernel<<<(N_NODES * 128 / 4 + 255) / 256, 256, 0, stream>>>(x, xbf, N_NODES * 128 / 4);

    const int nh8 = N_NODES * 8;

    // ----- layer 1: GAT(128 -> 8x32) + BN + ELU -----
    wtcast_kernel<<<(128 * 256 + 255) / 256, 256, 0, stream>>>(W1, wtbuf, 128, 256);
    gemm_bf16<<<dim3(2, (N_NODES + 127) / 128), 256, 0, stream>>>(xbf, wtbuf, hbuf, N_NODES, 256, 128);
    logits_bf<8, 32><<<(nh8 + 255) / 256, 256, 0, stream>>>(hbuf, as1, ad1, als, ald);
    edge_w_kernel<8><<<(E_TOT + 255) / 256, 256, 0, stream>>>(col, dstv, als, ald, wbuf);
    gat_gather_bf<256, 32, 8, true, true><<<(N_NODES + 3) / 4, 256, 0, stream>>>(
        row_ptr, col, hbuf, wbuf, b1, g1, be1, mn1, vr1, obuf);

    // ----- layer 2: GAT(256 -> 8x32) + BN + ELU -----
    wtcast_kernel<<<(256 * 256 + 255) / 256, 256, 0, stream>>>(W2, wtbuf, 256, 256);
    gemm_bf16<<<dim3(2, (N_NODES + 127) / 128), 256, 0, stream>>>(obuf, wtbuf, hbuf, N_NODES, 256, 256);
    logits_bf<8, 32><<<(nh8 + 255) / 256, 256, 0, stream>>>(hbuf, as2, ad2, als, ald);
    edge_w_kernel<8><<<(E_TOT + 255) / 256, 256, 0, stream>>>(col, dstv, als, ald, wbuf);
    gat_gather_bf<256, 32, 8, true, true><<<(N_NODES + 3) / 4, 256, 0, stream>>>(
        row_ptr, col, hbuf, wbuf, b2, g2, be2, mn2, vr2, obuf);

    // ----- layer 3: GAT(256 -> 1x128), heads=1 (mean == identity) -----
    wtcast_kernel<<<(256 * 128 + 255) / 256, 256, 0, stream>>>(W3, wtbuf, 256, 128);
    gemm_bf16<<<dim3(1, (N_NODES + 127) / 128), 256, 0, stream>>>(obuf, wtbuf, hbuf, N_NODES, 128, 256);
    logits_bf<1, 128><<<(N_NODES + 255) / 256, 256, 0, stream>>>(hbuf, as3, ad3, als, ald);
    edge_w_kernel<1><<<(E_TOT + 255) / 256, 256, 0, stream>>>(col, dstv, als, ald, wbuf);
    gat_gather_bf<128, 128, 1, false, false><<<(N_NODES + 7) / 8, 256, 0, stream>>>(
        row_ptr, col, hbuf, wbuf, b3, nullptr, nullptr, nullptr, nullptr, out);
}

// Round 5
// 574.911 us; speedup vs baseline: 14.5219x; 1.1837x over previous
//
#include <hip/hip_runtime.h>
#include <math.h>

#define N_NODES 50000
#define E_ORIG  800000
#define E_TOT   850000   // + self loops
#define SNB     49       // scan blocks: 49 * 1024 >= N_NODES

typedef __attribute__((ext_vector_type(8))) short short8;   // 8 bf16 (4 VGPRs)
typedef __attribute__((ext_vector_type(4))) float f32x4;    // MFMA acc

__device__ __forceinline__ short f2bf(float f) {            // fp32 -> bf16 RNE
    unsigned u = __builtin_bit_cast(unsigned, f);
    u += 0x7FFFu + ((u >> 16) & 1u);
    return (short)(u >> 16);
}
__device__ __forceinline__ float bf2f(short s) {
    unsigned u = ((unsigned)(unsigned short)s) << 16;
    return __builtin_bit_cast(float, u);
}

// ---------------- bf16 MFMA GEMM: C[M,N] = A[M,K] @ W[K,N], all bf16 ----------------
// 128x128 tile, BK=32, 256 threads = 4 waves (64x64 quadrant each, 4x4 MFMA tiles).
__global__ __launch_bounds__(256) void gemm_bf16(const short* __restrict__ A,
                                                 const short* __restrict__ Wt,   // W^T [N][K]
                                                 short* __restrict__ C,
                                                 int M, int N, int K)
{
    __shared__ short sA[128][40];
    __shared__ short sB[128][40];
    const int t    = threadIdx.x;
    const int wave = t >> 6, lane = t & 63;
    const int quad = lane >> 4, mrow = lane & 15;
    const int m0 = blockIdx.y * 128, n0 = blockIdx.x * 128;
    const int wm = (wave & 1) * 64, wn = (wave >> 1) * 64;

    f32x4 acc[4][4] = {};

    const int ra = t >> 2, ka = (t & 3) << 3;
    const int nb = t >> 1, kb = (t & 1) << 4;

    for (int k0 = 0; k0 < K; k0 += 32) {
#pragma unroll
        for (int rr = 0; rr < 2; ++rr) {
            int row = ra + rr * 64;
            int gm = m0 + row;
            int4 v = {0, 0, 0, 0};
            if (gm < M) v = *(const int4*)(A + (size_t)gm * K + k0 + ka);
            *(int4*)&sA[row][ka] = v;
        }
        {
            const int4* src = (const int4*)(Wt + (size_t)(n0 + nb) * K + k0 + kb);
            *(int4*)&sB[nb][kb]     = src[0];
            *(int4*)&sB[nb][kb + 8] = src[1];
        }
        __syncthreads();
        short8 af[4], bfr[4];
#pragma unroll
        for (int mi = 0; mi < 4; ++mi)
            af[mi] = *(const short8*)&sA[wm + mi * 16 + mrow][quad * 8];
#pragma unroll
        for (int ni = 0; ni < 4; ++ni)
            bfr[ni] = *(const short8*)&sB[wn + ni * 16 + mrow][quad * 8];
#pragma unroll
        for (int mi = 0; mi < 4; ++mi)
#pragma unroll
            for (int ni = 0; ni < 4; ++ni)
                acc[mi][ni] = __builtin_amdgcn_mfma_f32_16x16x32_bf16(af[mi], bfr[ni], acc[mi][ni], 0, 0, 0);
        __syncthreads();
    }
    // C/D layout: col = lane&15, row = quad*4 + reg
#pragma unroll
    for (int mi = 0; mi < 4; ++mi) {
#pragma unroll
        for (int ni = 0; ni < 4; ++ni) {
            int gn = n0 + wn + ni * 16 + mrow;
            int gmb = m0 + wm + mi * 16 + quad * 4;
#pragma unroll
            for (int r = 0; r < 4; ++r) {
                int gm = gmb + r;
                if (gm < M) C[(size_t)gm * N + gn] = f2bf(acc[mi][ni][r]);
            }
        }
    }
}

// ---------------- casts ----------------
__global__ void xcast_kernel(const float* __restrict__ x, short* __restrict__ xb, int total4)
{
    int i = blockIdx.x * blockDim.x + threadIdx.x;
    if (i >= total4) return;
    float4 v = ((const float4*)x)[i];
    short4 o; o.x = f2bf(v.x); o.y = f2bf(v.y); o.z = f2bf(v.z); o.w = f2bf(v.w);
    ((short4*)xb)[i] = o;
}

// all three W^T casts in one launch. layout: wt1[256][128], wt2[256][256], wt3[128][256]
__global__ void wtcast_all(const float* __restrict__ W1, const float* __restrict__ W2,
                           const float* __restrict__ W3, short* __restrict__ wt)
{
    int i = blockIdx.x * blockDim.x + threadIdx.x;
    if (i < 32768) {                       // W1: K=128, N=256
        int n = i / 128, k = i % 128;
        wt[i] = f2bf(W1[(size_t)k * 256 + n]);
    } else if (i < 98304) {                // W2: K=256, N=256
        int j = i - 32768;
        int n = j / 256, k = j % 256;
        wt[i] = f2bf(W2[(size_t)k * 256 + n]);
    } else if (i < 131072) {               // W3: K=256, N=128
        int j = i - 98304;
        int n = j / 256, k = j % 256;
        wt[i] = f2bf(W3[(size_t)k * 128 + n]);
    }
}

// ---------------- attention logits from bf16 h ----------------
template<int H, int C>
__global__ void logits_bf(const short* __restrict__ h,
                          const float* __restrict__ a_src,
                          const float* __restrict__ a_dst,
                          float* __restrict__ al_s, float* __restrict__ al_d)
{
    int i = blockIdx.x * blockDim.x + threadIdx.x;
    if (i >= N_NODES * H) return;
    int n = i / H, hh = i % H;
    const short* hp = h + (size_t)n * H * C + hh * C;
    const float* as = a_src + hh * C;
    const float* ad = a_dst + hh * C;
    float ss = 0.f, sd = 0.f;
#pragma unroll
    for (int c8 = 0; c8 < C; c8 += 8) {
        short8 hv = *(const short8*)(hp + c8);
#pragma unroll
        for (int j = 0; j < 8; ++j) {
            float v = bf2f(hv[j]);
            ss = fmaf(v, as[c8 + j], ss);
            sd = fmaf(v, ad[c8 + j], sd);
        }
    }
    al_s[i] = ss; al_d[i] = sd;
}

// ---------------- CSR build ----------------
__global__ void deg_kernel(const int* __restrict__ ei, int* __restrict__ deg)
{
    int e = blockIdx.x * blockDim.x + threadIdx.x;
    if (e >= E_TOT) return;
    int d = (e < E_ORIG) ? ei[E_ORIG + e] : e - E_ORIG;
    atomicAdd(&deg[d], 1);
}

// ---- 3-phase multi-block exclusive scan of deg -> row_ptr, cursor ----
__global__ __launch_bounds__(256) void scan_p1(const int* __restrict__ deg, int* __restrict__ bsum)
{
    __shared__ int wsum[4];
    int t = threadIdx.x;
    int base = blockIdx.x * 1024 + t * 4;
    int s = 0;
    if (base + 3 < N_NODES) {
        int4 v = *(const int4*)(deg + base);
        s = v.x + v.y + v.z + v.w;
    } else if (base < N_NODES) {
        for (int j = 0; j < 4 && base + j < N_NODES; ++j) s += deg[base + j];
    }
#pragma unroll
    for (int d = 32; d; d >>= 1) s += __shfl_down(s, d);
    if ((t & 63) == 0) wsum[t >> 6] = s;
    __syncthreads();
    if (t == 0) bsum[blockIdx.x] = wsum[0] + wsum[1] + wsum[2] + wsum[3];
}

__global__ void scan_p2(const int* __restrict__ bsum, int* __restrict__ bpre,
                        int* __restrict__ row_ptr)
{
    int t = threadIdx.x;   // 64 threads, one wave
    int v = (t < SNB) ? bsum[t] : 0;
    int inc = v;
#pragma unroll
    for (int d = 1; d < 64; d <<= 1) {
        int u = __shfl_up(inc, d);
        if (t >= d) inc += u;
    }
    if (t < SNB) bpre[t] = inc - v;
    if (t == SNB - 1) row_ptr[N_NODES] = inc;
}

__global__ __launch_bounds__(256) void scan_p3(const int* __restrict__ deg,
                                               const int* __restrict__ bpre,
                                               int* __restrict__ row_ptr,
                                               int* __restrict__ cursor)
{
    __shared__ int tsum[256];
    int t = threadIdx.x;
    int base = blockIdx.x * 1024 + t * 4;
    int d0 = 0, d1 = 0, d2 = 0, d3 = 0;
    if (base + 3 < N_NODES) {
        int4 v = *(const int4*)(deg + base);
        d0 = v.x; d1 = v.y; d2 = v.z; d3 = v.w;
    } else if (base < N_NODES) {
        d0 = deg[base];
        if (base + 1 < N_NODES) d1 = deg[base + 1];
        if (base + 2 < N_NODES) d2 = deg[base + 2];
    }
    int s = d0 + d1 + d2 + d3;
    tsum[t] = s;
    __syncthreads();
    for (int off = 1; off < 256; off <<= 1) {
        int u = (t >= off) ? tsum[t - off] : 0;
        __syncthreads();
        tsum[t] += u;
        __syncthreads();
    }
    int run = bpre[blockIdx.x] + tsum[t] - s;    // exclusive prefix for this thread's 4
    if (base < N_NODES)     { row_ptr[base]     = run; cursor[base]     = run; run += d0; }
    if (base + 1 < N_NODES) { row_ptr[base + 1] = run; cursor[base + 1] = run; run += d1; }
    if (base + 2 < N_NODES) { row_ptr[base + 2] = run; cursor[base + 2] = run; run += d2; }
    if (base + 3 < N_NODES) { row_ptr[base + 3] = run; cursor[base + 3] = run; }
}

__global__ void fill_kernel(const int* __restrict__ ei, int* __restrict__ cursor,
                            int* __restrict__ col, int* __restrict__ dstv)
{
    int e = blockIdx.x * blockDim.x + threadIdx.x;
    if (e >= E_TOT) return;
    int s, d;
    if (e < E_ORIG) { s = ei[e]; d = ei[E_ORIG + e]; } else { s = d = e - E_ORIG; }
    int pos = atomicAdd(&cursor[d], 1);
    col[pos] = s;
    dstv[pos] = d;
}

// ---------------- unnormalized edge weights ----------------
template<int H>
__global__ void edge_w_kernel(const int* __restrict__ col, const int* __restrict__ dstv,
                              const float* __restrict__ al_s, const float* __restrict__ al_d,
                              float* __restrict__ w)
{
    int e = blockIdx.x * blockDim.x + threadIdx.x;
    if (e >= E_TOT) return;
    int s = col[e], d = dstv[e];
#pragma unroll
    for (int h = 0; h < H; ++h) {
        float v = al_s[s * H + h] + al_d[d * H + h];
        v = v > 0.f ? v : 0.2f * v;
        w[(size_t)e * H + h] = expf(v);
    }
}

// ---------------- gather: out[n,c] = (sum_e w[e,head]*h[col[e],c]) / den (+ epilogue) ----------------
template<int HC, int C, int H, bool BN, bool OUTBF>
__global__ __launch_bounds__(256) void gat_gather_bf(const int* __restrict__ row_ptr,
                                                     const int* __restrict__ col,
                                                     const short* __restrict__ h,
                                                     const float* __restrict__ wv,
                                                     const float* __restrict__ bias,
                                                     const float* __restrict__ gamma,
                                                     const float* __restrict__ beta,
                                                     const float* __restrict__ mean,
                                                     const float* __restrict__ var,
                                                     void* __restrict__ outp)
{
    constexpr int TPN = HC / 4;
    constexpr int NPB = 256 / TPN;
    int n = blockIdx.x * NPB + threadIdx.x / TPN;
    if (n >= N_NODES) return;
    int lane = threadIdx.x % TPN;
    int c0 = lane * 4;
    int head = c0 / C;
    int beg = row_ptr[n], end = row_ptr[n + 1];
    float a0 = 0.f, a1 = 0.f, a2 = 0.f, a3 = 0.f, den = 0.f;
    int e = beg;
    for (; e + 1 < end; e += 2) {
        int s0 = col[e], s1 = col[e + 1];
        float w0 = wv[(size_t)e * H + head];
        float w1 = wv[(size_t)(e + 1) * H + head];
        short4 h0 = *(const short4*)(h + (size_t)s0 * HC + c0);
        short4 h1 = *(const short4*)(h + (size_t)s1 * HC + c0);
        den += w0 + w1;
        a0 = fmaf(w0, bf2f(h0.x), a0); a1 = fmaf(w0, bf2f(h0.y), a1);
        a2 = fmaf(w0, bf2f(h0.z), a2); a3 = fmaf(w0, bf2f(h0.w), a3);
        a0 = fmaf(w1, bf2f(h1.x), a0); a1 = fmaf(w1, bf2f(h1.y), a1);
        a2 = fmaf(w1, bf2f(h1.z), a2); a3 = fmaf(w1, bf2f(h1.w), a3);
    }
    if (e < end) {
        int s0 = col[e];
        float w0 = wv[(size_t)e * H + head];
        short4 h0 = *(const short4*)(h + (size_t)s0 * HC + c0);
        den += w0;
        a0 = fmaf(w0, bf2f(h0.x), a0); a1 = fmaf(w0, bf2f(h0.y), a1);
        a2 = fmaf(w0, bf2f(h0.z), a2); a3 = fmaf(w0, bf2f(h0.w), a3);
    }
    float inv = 1.f / den;
    float r[4] = { a0 * inv, a1 * inv, a2 * inv, a3 * inv };
#pragma unroll
    for (int j = 0; j < 4; ++j) {
        int c = c0 + j;
        float v = r[j] + bias[c];
        if (BN) {
            v = (v - mean[c]) * rsqrtf(var[c] + 1e-5f) * gamma[c] + beta[c];
            v = v > 0.f ? v : expm1f(v);   // ELU
        }
        r[j] = v;
    }
    if (OUTBF) {
        short4 o; o.x = f2bf(r[0]); o.y = f2bf(r[1]); o.z = f2bf(r[2]); o.w = f2bf(r[3]);
        *(short4*)((short*)outp + (size_t)n * HC + c0) = o;
    } else {
        *(float4*)((float*)outp + (size_t)n * HC + c0) = make_float4(r[0], r[1], r[2], r[3]);
    }
}

extern "C" void kernel_launch(void* const* d_in, const int* in_sizes, int n_in,
                              void* d_out, int out_size, void* d_ws, size_t ws_size,
                              hipStream_t stream)
{
    const float* x   = (const float*)d_in[0];
    const int*   ei  = (const int*)d_in[1];
    const float* W1  = (const float*)d_in[2];
    const float* as1 = (const float*)d_in[3];
    const float* ad1 = (const float*)d_in[4];
    const float* b1  = (const float*)d_in[5];
    const float* g1  = (const float*)d_in[6];
    const float* be1 = (const float*)d_in[7];
    const float* mn1 = (const float*)d_in[8];
    const float* vr1 = (const float*)d_in[9];
    const float* W2  = (const float*)d_in[10];
    const float* as2 = (const float*)d_in[11];
    const float* ad2 = (const float*)d_in[12];
    const float* b2  = (const float*)d_in[13];
    const float* g2  = (const float*)d_in[14];
    const float* be2 = (const float*)d_in[15];
    const float* mn2 = (const float*)d_in[16];
    const float* vr2 = (const float*)d_in[17];
    const float* W3  = (const float*)d_in[18];
    const float* as3 = (const float*)d_in[19];
    const float* ad3 = (const float*)d_in[20];
    const float* b3  = (const float*)d_in[21];

    char* p = (char*)d_ws;
    short* hbuf    = (short*)p; p += (size_t)N_NODES * 256 * 2;     // 25.6 MB (bf16 h)
    short* obuf    = (short*)p; p += (size_t)N_NODES * 256 * 2;     // 25.6 MB (bf16 layer out)
    short* xbf     = (short*)p; p += (size_t)N_NODES * 128 * 2;     // 12.8 MB (bf16 x)
    float* wbuf    = (float*)p; p += (size_t)E_TOT * 8 * 4;         // 27.2 MB (edge w)
    short* wtbuf   = (short*)p; p += (size_t)131072 * 2;            // 256 KB (wt1|wt2|wt3)
    float* als     = (float*)p; p += (size_t)N_NODES * 8 * 4;
    float* ald     = (float*)p; p += (size_t)N_NODES * 8 * 4;
    int*   row_ptr = (int*)p;   p += (size_t)(N_NODES + 1) * 4;
    int*   col     = (int*)p;   p += (size_t)E_TOT * 4;
    int*   dstv    = (int*)p;   p += (size_t)E_TOT * 4;
    int*   bsum    = (int*)p;   p += 64 * 4;
    int*   bpre    = (int*)p;   p += 64 * 4;
    // deg/cursor alias wbuf (dead before wbuf first written by edge_w)
    int*   deg     = (int*)wbuf;
    int*   cursor  = deg + N_NODES;

    short* wt1 = wtbuf;           // [256][128]
    short* wt2 = wtbuf + 32768;   // [256][256]
    short* wt3 = wtbuf + 98304;   // [128][256]

    float* out = (float*)d_out;

    // ----- CSR build + upfront casts -----
    hipMemsetAsync(deg, 0, (size_t)N_NODES * 4, stream);
    deg_kernel<<<(E_TOT + 255) / 256, 256, 0, stream>>>(ei, deg);
    scan_p1<<<SNB, 256, 0, stream>>>(deg, bsum);
    scan_p2<<<1, 64, 0, stream>>>(bsum, bpre, row_ptr);
    scan_p3<<<SNB, 256, 0, stream>>>(deg, bpre, row_ptr, cursor);
    fill_kernel<<<(E_TOT + 255) / 256, 256, 0, stream>>>(ei, cursor, col, dstv);
    xcast_kernel<<<(N_NODES * 128 / 4 + 255) / 256, 256, 0, stream>>>(x, xbf, N_NODES * 128 / 4);
    wtcast_all<<<(131072 + 255) / 256, 256, 0, stream>>>(W1, W2, W3, wtbuf);

    const int nh8 = N_NODES * 8;

    // ----- layer 1: GAT(128 -> 8x32) + BN + ELU -----
    gemm_bf16<<<dim3(2, (N_NODES + 127) / 128), 256, 0, stream>>>(xbf, wt1, hbuf, N_NODES, 256, 128);
    logits_bf<8, 32><<<(nh8 + 255) / 256, 256, 0, stream>>>(hbuf, as1, ad1, als, ald);
    edge_w_kernel<8><<<(E_TOT + 255) / 256, 256, 0, stream>>>(col, dstv, als, ald, wbuf);
    gat_gather_bf<256, 32, 8, true, true><<<(N_NODES + 3) / 4, 256, 0, stream>>>(
        row_ptr, col, hbuf, wbuf, b1, g1, be1, mn1, vr1, obuf);

    // ----- layer 2: GAT(256 -> 8x32) + BN + ELU -----
    gemm_bf16<<<dim3(2, (N_NODES + 127) / 128), 256, 0, stream>>>(obuf, wt2, hbuf, N_NODES, 256, 256);
    logits_bf<8, 32><<<(nh8 + 255) / 256, 256, 0, stream>>>(hbuf, as2, ad2, als, ald);
    edge_w_kernel<8><<<(E_TOT + 255) / 256, 256, 0, stream>>>(col, dstv, als, ald, wbuf);
    gat_gather_bf<256, 32, 8, true, true><<<(N_NODES + 3) / 4, 256, 0, stream>>>(
        row_ptr, col, hbuf, wbuf, b2, g2, be2, mn2, vr2, obuf);

    // ----- layer 3: GAT(256 -> 1x128), heads=1 (mean == identity) -----
    gemm_bf16<<<dim3(1, (N_NODES + 127) / 128), 256, 0, stream>>>(obuf, wt3, hbuf, N_NODES, 128, 256);
    logits_bf<1, 128><<<(N_NODES + 255) / 256, 256, 0, stream>>>(hbuf, as3, ad3, als, ald);
    edge_w_kernel<1><<<(E_TOT + 255) / 256, 256, 0, stream>>>(col, dstv, als, ald, wbuf);
    gat_gather_bf<128, 128, 1, false, false><<<(N_NODES + 7) / 8, 256, 0, stream>>>(
        row_ptr, col, hbuf, wbuf, b3, nullptr, nullptr, nullptr, nullptr, out);
}

// Round 6
// 564.066 us; speedup vs baseline: 14.8011x; 1.0192x over previous
//
#include <hip/hip_runtime.h>
#include <math.h>

#define N_NODES 50000
#define E_ORIG  800000
#define E_TOT   850000   // + self loops
#define SNB     49       // scan blocks: 49 * 1024 >= N_NODES
#define BPG     1563     // gather blocks per slice-phase: 1563 * 32 >= N_NODES

typedef __attribute__((ext_vector_type(8))) short short8;   // 8 bf16 (4 VGPRs)
typedef __attribute__((ext_vector_type(4))) float f32x4;    // MFMA acc

__device__ __forceinline__ short f2bf(float f) {            // fp32 -> bf16 RNE
    unsigned u = __builtin_bit_cast(unsigned, f);
    u += 0x7FFFu + ((u >> 16) & 1u);
    return (short)(u >> 16);
}
__device__ __forceinline__ float bf2f(short s) {
    unsigned u = ((unsigned)(unsigned short)s) << 16;
    return __builtin_bit_cast(float, u);
}

// ---------------- bf16 MFMA GEMM: C_t[blk][m][32] = (A[M,K] @ W[K,N]) sliced ----------------
// C written slice-major: 32-channel blocks, each slice contiguous [N_NODES][32].
__global__ __launch_bounds__(256) void gemm_bf16(const short* __restrict__ A,
                                                 const short* __restrict__ Wt,   // W^T [N][K]
                                                 short* __restrict__ C,          // [N/32][N_NODES][32]
                                                 int M, int N, int K)
{
    __shared__ short sA[128][40];
    __shared__ short sB[128][40];
    const int t    = threadIdx.x;
    const int wave = t >> 6, lane = t & 63;
    const int quad = lane >> 4, mrow = lane & 15;
    const int m0 = blockIdx.y * 128, n0 = blockIdx.x * 128;
    const int wm = (wave & 1) * 64, wn = (wave >> 1) * 64;

    f32x4 acc[4][4] = {};

    const int ra = t >> 2, ka = (t & 3) << 3;
    const int nb = t >> 1, kb = (t & 1) << 4;

    for (int k0 = 0; k0 < K; k0 += 32) {
#pragma unroll
        for (int rr = 0; rr < 2; ++rr) {
            int row = ra + rr * 64;
            int gm = m0 + row;
            int4 v = {0, 0, 0, 0};
            if (gm < M) v = *(const int4*)(A + (size_t)gm * K + k0 + ka);
            *(int4*)&sA[row][ka] = v;
        }
        {
            const int4* src = (const int4*)(Wt + (size_t)(n0 + nb) * K + k0 + kb);
            *(int4*)&sB[nb][kb]     = src[0];
            *(int4*)&sB[nb][kb + 8] = src[1];
        }
        __syncthreads();
        short8 af[4], bfr[4];
#pragma unroll
        for (int mi = 0; mi < 4; ++mi)
            af[mi] = *(const short8*)&sA[wm + mi * 16 + mrow][quad * 8];
#pragma unroll
        for (int ni = 0; ni < 4; ++ni)
            bfr[ni] = *(const short8*)&sB[wn + ni * 16 + mrow][quad * 8];
#pragma unroll
        for (int mi = 0; mi < 4; ++mi)
#pragma unroll
            for (int ni = 0; ni < 4; ++ni)
                acc[mi][ni] = __builtin_amdgcn_mfma_f32_16x16x32_bf16(af[mi], bfr[ni], acc[mi][ni], 0, 0, 0);
        __syncthreads();
    }
    // C/D layout: col = lane&15, row = quad*4 + reg; write slice-major
#pragma unroll
    for (int mi = 0; mi < 4; ++mi) {
#pragma unroll
        for (int ni = 0; ni < 4; ++ni) {
            int gn = n0 + wn + ni * 16 + mrow;
            size_t sbase = ((size_t)(gn >> 5) * N_NODES) * 32 + (gn & 31);
            int gmb = m0 + wm + mi * 16 + quad * 4;
#pragma unroll
            for (int r = 0; r < 4; ++r) {
                int gm = gmb + r;
                if (gm < M) C[sbase + (size_t)gm * 32] = f2bf(acc[mi][ni][r]);
            }
        }
    }
}

// ---------------- casts ----------------
__global__ void xcast_kernel(const float* __restrict__ x, short* __restrict__ xb, int total4)
{
    int i = blockIdx.x * blockDim.x + threadIdx.x;
    if (i >= total4) return;
    float4 v = ((const float4*)x)[i];
    short4 o; o.x = f2bf(v.x); o.y = f2bf(v.y); o.z = f2bf(v.z); o.w = f2bf(v.w);
    ((short4*)xb)[i] = o;
}

// all three W^T casts in one launch. layout: wt1[256][128], wt2[256][256], wt3[128][256]
__global__ void wtcast_all(const float* __restrict__ W1, const float* __restrict__ W2,
                           const float* __restrict__ W3, short* __restrict__ wt)
{
    int i = blockIdx.x * blockDim.x + threadIdx.x;
    if (i < 32768) {                       // W1: K=128, N=256
        int n = i / 128, k = i % 128;
        wt[i] = f2bf(W1[(size_t)k * 256 + n]);
    } else if (i < 98304) {                // W2: K=256, N=256
        int j = i - 32768;
        int n = j / 256, k = j % 256;
        wt[i] = f2bf(W2[(size_t)k * 256 + n]);
    } else if (i < 131072) {               // W3: K=256, N=128
        int j = i - 98304;
        int n = j / 256, k = j % 256;
        wt[i] = f2bf(W3[(size_t)k * 128 + n]);
    }
}

// ---------------- attention logits from slice-major bf16 h ----------------
// BPH = 32-ch blocks per head (1 for layers 1/2, 4 for layer 3)
template<int H, int BPH>
__global__ void logits_blk(const short* __restrict__ ht,
                           const float* __restrict__ a_src,
                           const float* __restrict__ a_dst,
                           float* __restrict__ al_s, float* __restrict__ al_d)
{
    int i = blockIdx.x * blockDim.x + threadIdx.x;
    if (i >= N_NODES * H) return;
    int n = i / H, hh = i % H;
    float ss = 0.f, sd = 0.f;
#pragma unroll
    for (int b = 0; b < BPH; ++b) {
        int blk = hh * BPH + b;
        const short* hp = ht + ((size_t)blk * N_NODES + n) * 32;
        const float* as = a_src + (hh * BPH + b) * 32;
        const float* ad = a_dst + (hh * BPH + b) * 32;
#pragma unroll
        for (int c8 = 0; c8 < 32; c8 += 8) {
            short8 hv = *(const short8*)(hp + c8);
#pragma unroll
            for (int j = 0; j < 8; ++j) {
                float v = bf2f(hv[j]);
                ss = fmaf(v, as[c8 + j], ss);
                sd = fmaf(v, ad[c8 + j], sd);
            }
        }
    }
    al_s[i] = ss; al_d[i] = sd;
}

// ---------------- CSR build ----------------
__global__ void deg_kernel(const int* __restrict__ ei, int* __restrict__ deg)
{
    int e = blockIdx.x * blockDim.x + threadIdx.x;
    if (e >= E_TOT) return;
    int d = (e < E_ORIG) ? ei[E_ORIG + e] : e - E_ORIG;
    atomicAdd(&deg[d], 1);
}

__global__ __launch_bounds__(256) void scan_p1(const int* __restrict__ deg, int* __restrict__ bsum)
{
    __shared__ int wsum[4];
    int t = threadIdx.x;
    int base = blockIdx.x * 1024 + t * 4;
    int s = 0;
    if (base + 3 < N_NODES) {
        int4 v = *(const int4*)(deg + base);
        s = v.x + v.y + v.z + v.w;
    } else if (base < N_NODES) {
        for (int j = 0; j < 4 && base + j < N_NODES; ++j) s += deg[base + j];
    }
#pragma unroll
    for (int d = 32; d; d >>= 1) s += __shfl_down(s, d);
    if ((t & 63) == 0) wsum[t >> 6] = s;
    __syncthreads();
    if (t == 0) bsum[blockIdx.x] = wsum[0] + wsum[1] + wsum[2] + wsum[3];
}

__global__ void scan_p2(const int* __restrict__ bsum, int* __restrict__ bpre,
                        int* __restrict__ row_ptr)
{
    int t = threadIdx.x;   // 64 threads, one wave
    int v = (t < SNB) ? bsum[t] : 0;
    int inc = v;
#pragma unroll
    for (int d = 1; d < 64; d <<= 1) {
        int u = __shfl_up(inc, d);
        if (t >= d) inc += u;
    }
    if (t < SNB) bpre[t] = inc - v;
    if (t == SNB - 1) row_ptr[N_NODES] = inc;
}

__global__ __launch_bounds__(256) void scan_p3(const int* __restrict__ deg,
                                               const int* __restrict__ bpre,
                                               int* __restrict__ row_ptr,
                                               int* __restrict__ cursor)
{
    __shared__ int tsum[256];
    int t = threadIdx.x;
    int base = blockIdx.x * 1024 + t * 4;
    int d0 = 0, d1 = 0, d2 = 0, d3 = 0;
    if (base + 3 < N_NODES) {
        int4 v = *(const int4*)(deg + base);
        d0 = v.x; d1 = v.y; d2 = v.z; d3 = v.w;
    } else if (base < N_NODES) {
        d0 = deg[base];
        if (base + 1 < N_NODES) d1 = deg[base + 1];
        if (base + 2 < N_NODES) d2 = deg[base + 2];
    }
    int s = d0 + d1 + d2 + d3;
    tsum[t] = s;
    __syncthreads();
    for (int off = 1; off < 256; off <<= 1) {
        int u = (t >= off) ? tsum[t - off] : 0;
        __syncthreads();
        tsum[t] += u;
        __syncthreads();
    }
    int run = bpre[blockIdx.x] + tsum[t] - s;
    if (base < N_NODES)     { row_ptr[base]     = run; cursor[base]     = run; run += d0; }
    if (base + 1 < N_NODES) { row_ptr[base + 1] = run; cursor[base + 1] = run; run += d1; }
    if (base + 2 < N_NODES) { row_ptr[base + 2] = run; cursor[base + 2] = run; run += d2; }
    if (base + 3 < N_NODES) { row_ptr[base + 3] = run; cursor[base + 3] = run; }
}

__global__ void fill_kernel(const int* __restrict__ ei, int* __restrict__ cursor,
                            int* __restrict__ col, int* __restrict__ dstv)
{
    int e = blockIdx.x * blockDim.x + threadIdx.x;
    if (e >= E_TOT) return;
    int s, d;
    if (e < E_ORIG) { s = ei[e]; d = ei[E_ORIG + e]; } else { s = d = e - E_ORIG; }
    int pos = atomicAdd(&cursor[d], 1);
    col[pos] = s;
    dstv[pos] = d;
}

// ---------------- unnormalized edge weights, head-major: w_t[h][e] ----------------
template<int H>
__global__ void edge_w_kernel(const int* __restrict__ col, const int* __restrict__ dstv,
                              const float* __restrict__ al_s, const float* __restrict__ al_d,
                              float* __restrict__ w)
{
    int e = blockIdx.x * blockDim.x + threadIdx.x;
    if (e >= E_TOT) return;
    int s = col[e], d = dstv[e];
#pragma unroll
    for (int h = 0; h < H; ++h) {
        float v = al_s[s * H + h] + al_d[d * H + h];
        v = v > 0.f ? v : 0.2f * v;
        w[(size_t)h * E_TOT + e] = expf(v);
    }
}

// ---------------- slice-blocked gather ----------------
// grid = NBLK slice-phases x BPG blocks; block = 32 nodes x 8 lanes (one 64B line per edge).
// Slice working set 3.2 MB < 4 MB/XCD L2; slice-major grid keeps one slice hot per phase.
template<int HC, int H, bool BN, bool OUTBF>
__global__ __launch_bounds__(256) void gat_gather_blk(const int* __restrict__ row_ptr,
                                                      const int* __restrict__ col,
                                                      const short* __restrict__ ht,
                                                      const float* __restrict__ wt,
                                                      const float* __restrict__ bias,
                                                      const float* __restrict__ gamma,
                                                      const float* __restrict__ beta,
                                                      const float* __restrict__ mean,
                                                      const float* __restrict__ var,
                                                      void* __restrict__ outp)
{
    constexpr int NBLK = HC / 32;
    int blk  = blockIdx.x / BPG;
    int nb   = blockIdx.x % BPG;
    int n = nb * 32 + (threadIdx.x >> 3);
    if (n >= N_NODES) return;
    int lane  = threadIdx.x & 7;
    int head  = (blk * H) / NBLK;          // layers 1/2: head=blk; layer 3: head=0
    int c_loc = lane * 4;
    const short* hb = ht + (size_t)blk * N_NODES * 32 + c_loc;
    const float* wh = wt + (size_t)head * E_TOT;
    int beg = row_ptr[n], end = row_ptr[n + 1];
    float a0 = 0.f, a1 = 0.f, a2 = 0.f, a3 = 0.f, den = 0.f;
    int e = beg;
    for (; e + 3 < end; e += 4) {          // 4 lines in flight per unit
        int s0 = col[e], s1 = col[e + 1], s2 = col[e + 2], s3 = col[e + 3];
        float w0 = wh[e], w1 = wh[e + 1], w2 = wh[e + 2], w3 = wh[e + 3];
        short4 h0 = *(const short4*)(hb + (size_t)s0 * 32);
        short4 h1 = *(const short4*)(hb + (size_t)s1 * 32);
        short4 h2 = *(const short4*)(hb + (size_t)s2 * 32);
        short4 h3 = *(const short4*)(hb + (size_t)s3 * 32);
        den += (w0 + w1) + (w2 + w3);
        a0 = fmaf(w0, bf2f(h0.x), a0); a1 = fmaf(w0, bf2f(h0.y), a1);
        a2 = fmaf(w0, bf2f(h0.z), a2); a3 = fmaf(w0, bf2f(h0.w), a3);
        a0 = fmaf(w1, bf2f(h1.x), a0); a1 = fmaf(w1, bf2f(h1.y), a1);
        a2 = fmaf(w1, bf2f(h1.z), a2); a3 = fmaf(w1, bf2f(h1.w), a3);
        a0 = fmaf(w2, bf2f(h2.x), a0); a1 = fmaf(w2, bf2f(h2.y), a1);
        a2 = fmaf(w2, bf2f(h2.z), a2); a3 = fmaf(w2, bf2f(h2.w), a3);
        a0 = fmaf(w3, bf2f(h3.x), a0); a1 = fmaf(w3, bf2f(h3.y), a1);
        a2 = fmaf(w3, bf2f(h3.z), a2); a3 = fmaf(w3, bf2f(h3.w), a3);
    }
    for (; e < end; ++e) {
        int s0 = col[e];
        float w0 = wh[e];
        short4 h0 = *(const short4*)(hb + (size_t)s0 * 32);
        den += w0;
        a0 = fmaf(w0, bf2f(h0.x), a0); a1 = fmaf(w0, bf2f(h0.y), a1);
        a2 = fmaf(w0, bf2f(h0.z), a2); a3 = fmaf(w0, bf2f(h0.w), a3);
    }
    float inv = 1.f / den;
    float r[4] = { a0 * inv, a1 * inv, a2 * inv, a3 * inv };
    int cb = blk * 32 + c_loc;
#pragma unroll
    for (int j = 0; j < 4; ++j) {
        int c = cb + j;
        float v = r[j] + bias[c];
        if (BN) {
            v = (v - mean[c]) * rsqrtf(var[c] + 1e-5f) * gamma[c] + beta[c];
            v = v > 0.f ? v : expm1f(v);   // ELU
        }
        r[j] = v;
    }
    if (OUTBF) {
        short4 o; o.x = f2bf(r[0]); o.y = f2bf(r[1]); o.z = f2bf(r[2]); o.w = f2bf(r[3]);
        *(short4*)((short*)outp + (size_t)n * HC + cb) = o;
    } else {
        *(float4*)((float*)outp + (size_t)n * HC + cb) = make_float4(r[0], r[1], r[2], r[3]);
    }
}

extern "C" void kernel_launch(void* const* d_in, const int* in_sizes, int n_in,
                              void* d_out, int out_size, void* d_ws, size_t ws_size,
                              hipStream_t stream)
{
    const float* x   = (const float*)d_in[0];
    const int*   ei  = (const int*)d_in[1];
    const float* W1  = (const float*)d_in[2];
    const float* as1 = (const float*)d_in[3];
    const float* ad1 = (const float*)d_in[4];
    const float* b1  = (const float*)d_in[5];
    const float* g1  = (const float*)d_in[6];
    const float* be1 = (const float*)d_in[7];
    const float* mn1 = (const float*)d_in[8];
    const float* vr1 = (const float*)d_in[9];
    const float* W2  = (const float*)d_in[10];
    const float* as2 = (const float*)d_in[11];
    const float* ad2 = (const float*)d_in[12];
    const float* b2  = (const float*)d_in[13];
    const float* g2  = (const float*)d_in[14];
    const float* be2 = (const float*)d_in[15];
    const float* mn2 = (const float*)d_in[16];
    const float* vr2 = (const float*)d_in[17];
    const float* W3  = (const float*)d_in[18];
    const float* as3 = (const float*)d_in[19];
    const float* ad3 = (const float*)d_in[20];
    const float* b3  = (const float*)d_in[21];

    char* p = (char*)d_ws;
    short* hbuf    = (short*)p; p += (size_t)N_NODES * 256 * 2;     // 25.6 MB (slice-major h)
    short* obuf    = (short*)p; p += (size_t)N_NODES * 256 * 2;     // 25.6 MB (row-major layer out)
    short* xbf     = (short*)p; p += (size_t)N_NODES * 128 * 2;     // 12.8 MB (bf16 x)
    float* wbuf    = (float*)p; p += (size_t)E_TOT * 8 * 4;         // 27.2 MB (w_t[h][e])
    short* wtbuf   = (short*)p; p += (size_t)131072 * 2;            // 256 KB (wt1|wt2|wt3)
    float* als     = (float*)p; p += (size_t)N_NODES * 8 * 4;
    float* ald     = (float*)p; p += (size_t)N_NODES * 8 * 4;
    int*   row_ptr = (int*)p;   p += (size_t)(N_NODES + 1) * 4;
    int*   col     = (int*)p;   p += (size_t)E_TOT * 4;
    int*   dstv    = (int*)p;   p += (size_t)E_TOT * 4;
    int*   bsum    = (int*)p;   p += 64 * 4;
    int*   bpre    = (int*)p;   p += 64 * 4;
    // deg/cursor alias wbuf (dead before wbuf first written by edge_w)
    int*   deg     = (int*)wbuf;
    int*   cursor  = deg + N_NODES;

    short* wt1 = wtbuf;           // [256][128]
    short* wt2 = wtbuf + 32768;   // [256][256]
    short* wt3 = wtbuf + 98304;   // [128][256]

    float* out = (float*)d_out;

    // ----- CSR build + upfront casts -----
    hipMemsetAsync(deg, 0, (size_t)N_NODES * 4, stream);
    deg_kernel<<<(E_TOT + 255) / 256, 256, 0, stream>>>(ei, deg);
    scan_p1<<<SNB, 256, 0, stream>>>(deg, bsum);
    scan_p2<<<1, 64, 0, stream>>>(bsum, bpre, row_ptr);
    scan_p3<<<SNB, 256, 0, stream>>>(deg, bpre, row_ptr, cursor);
    fill_kernel<<<(E_TOT + 255) / 256, 256, 0, stream>>>(ei, cursor, col, dstv);
    xcast_kernel<<<(N_NODES * 128 / 4 + 255) / 256, 256, 0, stream>>>(x, xbf, N_NODES * 128 / 4);
    wtcast_all<<<(131072 + 255) / 256, 256, 0, stream>>>(W1, W2, W3, wtbuf);

    const int nh8 = N_NODES * 8;

    // ----- layer 1: GAT(128 -> 8x32) + BN + ELU -----
    gemm_bf16<<<dim3(2, (N_NODES + 127) / 128), 256, 0, stream>>>(xbf, wt1, hbuf, N_NODES, 256, 128);
    logits_blk<8, 1><<<(nh8 + 255) / 256, 256, 0, stream>>>(hbuf, as1, ad1, als, ald);
    edge_w_kernel<8><<<(E_TOT + 255) / 256, 256, 0, stream>>>(col, dstv, als, ald, wbuf);
    gat_gather_blk<256, 8, true, true><<<BPG * 8, 256, 0, stream>>>(
        row_ptr, col, hbuf, wbuf, b1, g1, be1, mn1, vr1, obuf);

    // ----- layer 2: GAT(256 -> 8x32) + BN + ELU -----
    gemm_bf16<<<dim3(2, (N_NODES + 127) / 128), 256, 0, stream>>>(obuf, wt2, hbuf, N_NODES, 256, 256);
    logits_blk<8, 1><<<(nh8 + 255) / 256, 256, 0, stream>>>(hbuf, as2, ad2, als, ald);
    edge_w_kernel<8><<<(E_TOT + 255) / 256, 256, 0, stream>>>(col, dstv, als, ald, wbuf);
    gat_gather_blk<256, 8, true, true><<<BPG * 8, 256, 0, stream>>>(
        row_ptr, col, hbuf, wbuf, b2, g2, be2, mn2, vr2, obuf);

    // ----- layer 3: GAT(256 -> 1x128), heads=1 (mean == identity) -----
    gemm_bf16<<<dim3(1, (N_NODES + 127) / 128), 256, 0, stream>>>(obuf, wt3, hbuf, N_NODES, 128, 256);
    logits_blk<1, 4><<<(N_NODES + 255) / 256, 256, 0, stream>>>(hbuf, as3, ad3, als, ald);
    edge_w_kernel<1><<<(E_TOT + 255) / 256, 256, 0, stream>>>(col, dstv, als, ald, wbuf);
    gat_gather_blk<128, 1, false, false><<<BPG * 4, 256, 0, stream>>>(
        row_ptr, col, hbuf, wbuf, b3, nullptr, nullptr, nullptr, nullptr, out);
}